// Round 11
// baseline (160.767 us; speedup 1.0000x reference)
//
#include <hip/hip_runtime.h>

#define DD 256
#define BB 8
#define NA 360
#define WT 32            // w per tile
#define HT 32            // h per tile
#define MAXC 46          // max window cols/rows: (|c|+|s|)*31 <= 43.9 -> <=46
#define WSTR 47          // LDS row stride in uint4 (odd -> bank phase rotates)

typedef _Float16 half2_t __attribute__((ext_vector_type(2)));

#if defined(__has_builtin)
#if __has_builtin(__builtin_elementwise_fma)
#define PKFMA(a, b, c) __builtin_elementwise_fma((a), (b), (c))
#endif
#endif
#ifndef PKFMA
#define PKFMA(a, b, c) ((a) * (b) + (c))
#endif

__device__ __forceinline__ half2_t h2(unsigned u) {
    return __builtin_bit_cast(half2_t, u);
}
__device__ __forceinline__ half2_t bcast2(float w) {   // v_cvt_pkrtz (w,w)
    return __builtin_bit_cast(half2_t, __builtin_amdgcn_cvt_pkrtz(w, w));
}
__device__ __forceinline__ unsigned pk_f16(float a, float b) {
    unsigned short ua = __builtin_bit_cast(unsigned short, (_Float16)a);
    unsigned short ub = __builtin_bit_cast(unsigned short, (_Float16)b);
    return (unsigned)ua | ((unsigned)ub << 16);
}

// ---- pack: (B,1,D,D) fp32 -> f16x8/pixel, row-major only ------------------
__global__ __launch_bounds__(256) void pack_f16(const float* __restrict__ x,
                                                uint4* __restrict__ pN) {
    const int pix = blockIdx.x * 256 + threadIdx.x;
    uint4 v;
    v.x = pk_f16(x[0 * DD * DD + pix], x[1 * DD * DD + pix]);
    v.y = pk_f16(x[2 * DD * DD + pix], x[3 * DD * DD + pix]);
    v.z = pk_f16(x[4 * DD * DD + pix], x[5 * DD * DD + pix]);
    v.w = pk_f16(x[6 * DD * DD + pix], x[7 * DD * DD + pix]);
    pN[pix] = v;
}

// ---- radon: LDS-windowed gather -------------------------------------------
// Block = (angle, 32w x 32h tile). Stage the tile's sample bounding box into
// LDS (<=46x46 px, 34.6 KB), then gather corners via ds_read_b128 instead of
// scattered global loads (TA 32cyc/load -> LDS ~8-12cyc/load).
__global__ __launch_bounds__(256) void radon_lds(const uint4* __restrict__ pN,
                                                 float* __restrict__ out) {
    __shared__ __align__(16) unsigned char smem[MAXC * WSTR * 16];  // 34.6 KB
    uint4* win = (uint4*)smem;

    const int a   = blockIdx.x;          // angle
    const int wt  = blockIdx.y & 7;      // w tile
    const int ht  = blockIdx.y >> 3;     // h tile
    const int tid = threadIdx.x;

    const float ang = (float)a * 0.5f;
    const float t = ang * 0.017453292519943295f;
    const float s = sinf(t);
    const float c = cosf(t);

    const int w0 = wt * WT, h0 = ht * HT;

    // ---- window bounds from 4 tile corners (same fp path as per-sample;
    //      fmaf is monotone, so interior samples lie within corner extremes)
    float fxmin = 1e30f, fxmax = -1e30f, fymin = 1e30f, fymax = -1e30f;
#pragma unroll
    for (int i = 0; i < 4; ++i) {
        const float uwc = (float)(w0 + (i & 1) * (WT - 1)) - 127.5f;
        const float uhc = (float)(h0 + (i >> 1) * (HT - 1)) - 127.5f;
        const float axc = fmaf(c, uwc, 127.5f);
        const float ayc = fmaf(s, uwc, 127.5f);
        const float ixc = fmaf(-s, uhc, axc);
        const float iyc = fmaf(c, uhc, ayc);
        fxmin = fminf(fxmin, ixc); fxmax = fmaxf(fxmax, ixc);
        fymin = fminf(fymin, iyc); fymax = fmaxf(fymax, iyc);
    }
    // clamped bounds; all clamped corner indices land in [lo, hi] (clamp is
    // monotone, x0>=floor(fxmin), x0+1<=floor(fxmax)+1, incl. off-image tiles)
    const int x_lo = min(max((int)floorf(fxmin), 0), 255);
    const int x_hi = min(max((int)floorf(fxmax) + 1, 0), 255);
    const int y_lo = min(max((int)floorf(fymin), 0), 255);
    const int y_hi = min(max((int)floorf(fymax) + 1, 0), 255);
    const int ncols = x_hi - x_lo + 1;   // <= 46
    const int nrows = y_hi - y_lo + 1;   // <= 46

    // ---- stage window (coalesced: one row segment per wave-iter)
    {
        const int cl = tid & 63;
        const int r0 = tid >> 6;
        for (int r = r0; r < nrows; r += 4)
            if (cl < ncols)
                win[r * WSTR + cl] = pN[(y_lo + r) * DD + x_lo + cl];
    }
    __syncthreads();

    // ---- compute: wave g, lane (hp, wl); h = h0 + 2g + hp + 8k
    const int g    = tid >> 6;
    const int lane = tid & 63;
    const int hp   = lane >> 5;
    const int wl   = lane & 31;

    const float uw = (float)(w0 + wl) - 127.5f;
    const float ax = fmaf(c, uw, 127.5f);
    const float ay = fmaf(s, uw, 127.5f);

    half2_t acc2[4];
#pragma unroll
    for (int j = 0; j < 4; ++j) acc2[j] = half2_t{(_Float16)0, (_Float16)0};

#pragma unroll
    for (int k = 0; k < 4; ++k) {
        const int h = h0 + 2 * g + hp + 8 * k;
        const float uh = (float)h - 127.5f;
        const float ix = fmaf(-s, uh, ax);
        const float iy = fmaf(c, uh, ay);
        const float x0f = floorf(ix), y0f = floorf(iy);
        const float wx1 = ix - x0f, wy1 = iy - y0f;
        const float wx0 = 1.f - wx1, wy0 = 1.f - wy1;
        const int x0 = (int)x0f, y0 = (int)y0f;
        const float vx0 = ((unsigned)x0 < 256u) ? wx0 : 0.f;
        const float vx1 = ((unsigned)(x0 + 1) < 256u) ? wx1 : 0.f;
        const float vy0 = ((unsigned)y0 < 256u) ? wy0 : 0.f;
        const float vy1 = ((unsigned)(y0 + 1) < 256u) ? wy1 : 0.f;
        const int rx0 = min(max(x0, 0), 255) - x_lo;
        const int rx1 = min(max(x0 + 1, 0), 255) - x_lo;
        const int ry0 = min(max(y0, 0), 255) - y_lo;
        const int ry1 = min(max(y0 + 1, 0), 255) - y_lo;

        const uint4 q00 = win[ry0 * WSTR + rx0];
        const uint4 q10 = win[ry0 * WSTR + rx1];
        const uint4 q01 = win[ry1 * WSTR + rx0];
        const uint4 q11 = win[ry1 * WSTR + rx1];

        const half2_t w00 = bcast2(vx0 * vy0);
        const half2_t w10 = bcast2(vx1 * vy0);
        const half2_t w01 = bcast2(vx0 * vy1);
        const half2_t w11 = bcast2(vx1 * vy1);

        acc2[0] = PKFMA(h2(q00.x), w00, acc2[0]);
        acc2[1] = PKFMA(h2(q00.y), w00, acc2[1]);
        acc2[2] = PKFMA(h2(q00.z), w00, acc2[2]);
        acc2[3] = PKFMA(h2(q00.w), w00, acc2[3]);
        acc2[0] = PKFMA(h2(q10.x), w10, acc2[0]);
        acc2[1] = PKFMA(h2(q10.y), w10, acc2[1]);
        acc2[2] = PKFMA(h2(q10.z), w10, acc2[2]);
        acc2[3] = PKFMA(h2(q10.w), w10, acc2[3]);
        acc2[0] = PKFMA(h2(q01.x), w01, acc2[0]);
        acc2[1] = PKFMA(h2(q01.y), w01, acc2[1]);
        acc2[2] = PKFMA(h2(q01.z), w01, acc2[2]);
        acc2[3] = PKFMA(h2(q01.w), w01, acc2[3]);
        acc2[0] = PKFMA(h2(q11.x), w11, acc2[0]);
        acc2[1] = PKFMA(h2(q11.y), w11, acc2[1]);
        acc2[2] = PKFMA(h2(q11.z), w11, acc2[2]);
        acc2[3] = PKFMA(h2(q11.w), w11, acc2[3]);
    }

    float acc[BB];
#pragma unroll
    for (int j = 0; j < 4; ++j) {
        acc[2 * j]     = (float)acc2[j].x;
        acc[2 * j + 1] = (float)acc2[j].y;
    }

    // ---- reduce 8 (g,hp) partials per (w,b); smem reused after barrier
    __syncthreads();                       // all win reads done
    float* part = (float*)smem;            // [8][32][8] = 8 KB
    const int p = g * 2 + hp;
#pragma unroll
    for (int b = 0; b < BB; b += 4)
        *(float4*)&part[(p * 32 + wl) * BB + b] =
            make_float4(acc[b], acc[b + 1], acc[b + 2], acc[b + 3]);
    __syncthreads();

    const float sc = 1.0f / 256.0f;
    const int wl2 = tid & 31, b2 = tid >> 5;
    float v = 0.f;
#pragma unroll
    for (int p2 = 0; p2 < 8; ++p2) v += part[(p2 * 32 + wl2) * BB + b2];
    atomicAdd(out + (size_t)b2 * NA * DD + (size_t)a * DD + w0 + wl2, v * sc);
}

// ---- fallback (ws too small): direct fp32 gather with atomics -------------
__global__ __launch_bounds__(256) void radon_direct(const float* __restrict__ x,
                                                    float* __restrict__ out) {
    const int a  = blockIdx.x;
    const int hc = blockIdx.y;
    const int w  = threadIdx.x;
    const float ang = (float)a * 0.5f;
    const float t = ang * 0.017453292519943295f;
    const float s = sinf(t);
    const float c = cosf(t);
    const float uw = (float)w - 127.5f;
    const float ax = fmaf(c, uw, 127.5f);
    const float ay = fmaf(s, uw, 127.5f);

    float acc[BB];
#pragma unroll
    for (int b = 0; b < BB; ++b) acc[b] = 0.f;

    const int h0 = hc * 32;
    for (int i = 0; i < 32; ++i) {
        const float uh = (float)(h0 + i) - 127.5f;
        const float ix = fmaf(-s, uh, ax);
        const float iy = fmaf(c, uh, ay);
        const float x0f = floorf(ix), y0f = floorf(iy);
        const float wx1 = ix - x0f, wy1 = iy - y0f;
        const float wx0 = 1.f - wx1, wy0 = 1.f - wy1;
        const int x0 = (int)x0f, y0 = (int)y0f;
        const float vx0 = ((unsigned)x0 < 256u) ? wx0 : 0.f;
        const float vx1 = ((unsigned)(x0 + 1) < 256u) ? wx1 : 0.f;
        const float vy0 = ((unsigned)y0 < 256u) ? wy0 : 0.f;
        const float vy1 = ((unsigned)(y0 + 1) < 256u) ? wy1 : 0.f;
        const int x0c = min(max(x0, 0), 255);
        const int x1c = min(max(x0 + 1, 0), 255);
        const int y0c = min(max(y0, 0), 255);
        const int y1c = min(max(y0 + 1, 0), 255);
        const float w00 = vx0 * vy0, w10 = vx1 * vy0;
        const float w01 = vx0 * vy1, w11 = vx1 * vy1;
        const int l00 = y0c * DD + x0c, l10 = y0c * DD + x1c;
        const int l01 = y1c * DD + x0c, l11 = y1c * DD + x1c;
#pragma unroll
        for (int b = 0; b < BB; ++b) {
            const float* ib = x + (size_t)b * DD * DD;
            acc[b] = fmaf(ib[l00], w00, acc[b]);
            acc[b] = fmaf(ib[l10], w10, acc[b]);
            acc[b] = fmaf(ib[l01], w01, acc[b]);
            acc[b] = fmaf(ib[l11], w11, acc[b]);
        }
    }

    const float sc = 1.0f / 256.0f;
    float* o = out + (size_t)a * DD + w;
#pragma unroll
    for (int b = 0; b < BB; ++b)
        atomicAdd(o + (size_t)b * NA * DD, acc[b] * sc);
}

extern "C" void kernel_launch(void* const* d_in, const int* in_sizes, int n_in,
                              void* d_out, int out_size, void* d_ws, size_t ws_size,
                              hipStream_t stream) {
    const float* x = (const float*)d_in[0];
    float* out = (float*)d_out;

    // atomic accumulation (8 htile writers/output) -> zero the poisoned out
    (void)hipMemsetAsync(d_out, 0, (size_t)out_size * sizeof(float), stream);

    const size_t need = (size_t)DD * DD * sizeof(uint4);  // 1 MiB
    if (ws_size >= need) {
        uint4* pN = (uint4*)d_ws;
        pack_f16<<<DD * DD / 256, 256, 0, stream>>>(x, pN);
        radon_lds<<<dim3(NA, 64), 256, 0, stream>>>(pN, out);
    } else {
        radon_direct<<<dim3(NA, 8), 256, 0, stream>>>(x, out);
    }
}

// Round 12
// 124.772 us; speedup vs baseline: 1.2885x; 1.2885x over previous
//
#include <hip/hip_runtime.h>

#define DD 256
#define BB 8
#define NA 360

typedef _Float16 half2_t __attribute__((ext_vector_type(2)));

#if defined(__has_builtin)
#if __has_builtin(__builtin_elementwise_fma)
#define PKFMA(a, b, c) __builtin_elementwise_fma((a), (b), (c))
#endif
#endif
#ifndef PKFMA
#define PKFMA(a, b, c) ((a) * (b) + (c))
#endif

__device__ __forceinline__ half2_t h2(unsigned u) {
    return __builtin_bit_cast(half2_t, u);
}
__device__ __forceinline__ half2_t bcast2(float w) {   // v_cvt_pkrtz (w,w)
    return __builtin_bit_cast(half2_t, __builtin_amdgcn_cvt_pkrtz(w, w));
}
__device__ __forceinline__ unsigned pk_f16(float a, float b) {
    unsigned short ua = __builtin_bit_cast(unsigned short, (_Float16)a);
    unsigned short ub = __builtin_bit_cast(unsigned short, (_Float16)b);
    return (unsigned)ua | ((unsigned)ub << 16);
}

// ---- pack: (B,1,D,D) fp32 -> f16x8/pixel pN + transposed pT ---------------
// 256 blocks (16x16 tiles) so pack saturates all 256 CUs (~1.5us).
__global__ __launch_bounds__(256) void pack_f16(const float* __restrict__ x,
                                                uint4* __restrict__ pN,
                                                uint4* __restrict__ pT) {
    __shared__ uint4 t[16][17];
    const int tx = threadIdx.x & 15;
    const int ty = threadIdx.x >> 4;              // 0..15
    const int x0 = (blockIdx.x & 15) * 16;
    const int y0 = (blockIdx.x >> 4) * 16;

    const int pix = (y0 + ty) * DD + x0 + tx;
    uint4 v;
    v.x = pk_f16(x[0 * DD * DD + pix], x[1 * DD * DD + pix]);
    v.y = pk_f16(x[2 * DD * DD + pix], x[3 * DD * DD + pix]);
    v.z = pk_f16(x[4 * DD * DD + pix], x[5 * DD * DD + pix]);
    v.w = pk_f16(x[6 * DD * DD + pix], x[7 * DD * DD + pix]);
    pN[pix] = v;                                   // coalesced
    t[ty][tx] = v;
    __syncthreads();
    // pT[xx*D+yy] = img[yy][xx]
    pT[(x0 + ty) * DD + y0 + tx] = t[tx][ty];      // coalesced
}

// ---- radon (R7/R10 structure — at the scattered-gather address floor) -----
// block = (angle, w-quarter); 4 waves = interleaved h-phases; LDS reduce;
// exclusive coalesced stores (no atomics, no output memset needed).
// Per h-step: 4 scattered b128 loads. Floor model (validated R10 to 0.4%):
// 94.4M gathers / 64 lanes * 32 cyc TA addr-processing / 256 CU / 2.4 GHz
// = 76.8 us. Tested escapes all regress: fewer-lines (R2 flat), pair-layout
// (R5 +27%), 2x TLP (R8 flat), fused barrier (R9 +30%), LDS window (R11 +53%).
__global__ __launch_bounds__(256) void radon_pk(const uint4* __restrict__ pN,
                                                const uint4* __restrict__ pT,
                                                float* __restrict__ out) {
    const int a    = blockIdx.x;            // angle
    const int wseg = blockIdx.y;            // 0..3
    const int g    = threadIdx.x >> 6;      // wave = h-phase 0..3
    const int lane = threadIdx.x & 63;
    const int w    = wseg * 64 + lane;

    const float ang = (float)a * 0.5f;
    const float t = ang * 0.017453292519943295f;
    const float s = sinf(t);
    const float c = cosf(t);

    const float uw  = (float)w - 127.5f;
    const float axN = fmaf(c, uw, 127.5f);
    const float ayN = fmaf(s, uw, 127.5f);

    // inner coord = contiguous dim of chosen layout (h-step = min(|s|,|c|))
    const uint4* __restrict__ P;
    float ax, dx, ay, dy;                    // inner = ax+dx*uh, row = ay+dy*uh
    if (fabsf(s) <= fabsf(c)) { P = pN; ax = axN; dx = -s; ay = ayN; dy = c;  }
    else                      { P = pT; ax = ayN; dx = c;  ay = axN; dy = -s; }

    half2_t acc2[4];
#pragma unroll
    for (int j = 0; j < 4; ++j) acc2[j] = half2_t{(_Float16)0, (_Float16)0};

    // h = g + 4*i : the block's 4 waves march through adjacent h together
#pragma unroll 4
    for (int i = 0; i < 64; ++i) {
        const float uh = (float)(g + 4 * i) - 127.5f;
        const float ix = fmaf(dx, uh, ax);
        const float iy = fmaf(dy, uh, ay);
        const float x0f = floorf(ix), y0f = floorf(iy);
        const float wx1 = ix - x0f, wy1 = iy - y0f;
        const float wx0 = 1.f - wx1, wy0 = 1.f - wy1;
        const int x0 = (int)x0f, y0 = (int)y0f;
        const float vx0 = ((unsigned)x0 < 256u) ? wx0 : 0.f;
        const float vx1 = ((unsigned)(x0 + 1) < 256u) ? wx1 : 0.f;
        const float vy0 = ((unsigned)y0 < 256u) ? wy0 : 0.f;
        const float vy1 = ((unsigned)(y0 + 1) < 256u) ? wy1 : 0.f;
        const int x0c = min(max(x0, 0), 255);
        const int x1c = min(max(x0 + 1, 0), 255);
        const int y0c = min(max(y0, 0), 255);
        const int y1c = min(max(y0 + 1, 0), 255);

        const uint4 q00 = P[y0c * DD + x0c];
        const uint4 q10 = P[y0c * DD + x1c];
        const uint4 q01 = P[y1c * DD + x0c];
        const uint4 q11 = P[y1c * DD + x1c];

        const half2_t w00 = bcast2(vx0 * vy0);
        const half2_t w10 = bcast2(vx1 * vy0);
        const half2_t w01 = bcast2(vx0 * vy1);
        const half2_t w11 = bcast2(vx1 * vy1);

        acc2[0] = PKFMA(h2(q00.x), w00, acc2[0]);
        acc2[1] = PKFMA(h2(q00.y), w00, acc2[1]);
        acc2[2] = PKFMA(h2(q00.z), w00, acc2[2]);
        acc2[3] = PKFMA(h2(q00.w), w00, acc2[3]);
        acc2[0] = PKFMA(h2(q10.x), w10, acc2[0]);
        acc2[1] = PKFMA(h2(q10.y), w10, acc2[1]);
        acc2[2] = PKFMA(h2(q10.z), w10, acc2[2]);
        acc2[3] = PKFMA(h2(q10.w), w10, acc2[3]);
        acc2[0] = PKFMA(h2(q01.x), w01, acc2[0]);
        acc2[1] = PKFMA(h2(q01.y), w01, acc2[1]);
        acc2[2] = PKFMA(h2(q01.z), w01, acc2[2]);
        acc2[3] = PKFMA(h2(q01.w), w01, acc2[3]);
        acc2[0] = PKFMA(h2(q11.x), w11, acc2[0]);
        acc2[1] = PKFMA(h2(q11.y), w11, acc2[1]);
        acc2[2] = PKFMA(h2(q11.z), w11, acc2[2]);
        acc2[3] = PKFMA(h2(q11.w), w11, acc2[3]);
    }

    // ---- widen to f32, in-block reduction over 4 h-phases, exclusive store
    float acc[BB];
#pragma unroll
    for (int j = 0; j < 4; ++j) {
        acc[2 * j]     = (float)acc2[j].x;
        acc[2 * j + 1] = (float)acc2[j].y;
    }

    __shared__ float part[4][64][BB];        // 8 KB
#pragma unroll
    for (int b = 0; b < BB; b += 4)
        *(float4*)&part[g][lane][b] = make_float4(acc[b], acc[b + 1], acc[b + 2], acc[b + 3]);
    __syncthreads();

    const float sc = 1.0f / 256.0f;
#pragma unroll
    for (int k = 0; k < 2; ++k) {
        const int id = threadIdx.x + k * 256;  // 0..511 -> (b, wl)
        const int b  = id >> 6;
        const int wl = id & 63;
        const float v = part[0][wl][b] + part[1][wl][b] + part[2][wl][b] + part[3][wl][b];
        out[(size_t)b * NA * DD + (size_t)a * DD + wseg * 64 + wl] = v * sc;
    }
}

// ---- fallback (ws too small): direct fp32 gather with atomics -------------
__global__ __launch_bounds__(256) void radon_direct(const float* __restrict__ x,
                                                    float* __restrict__ out) {
    const int a  = blockIdx.x;
    const int hc = blockIdx.y;
    const int w  = threadIdx.x;
    const float ang = (float)a * 0.5f;
    const float t = ang * 0.017453292519943295f;
    const float s = sinf(t);
    const float c = cosf(t);
    const float uw = (float)w - 127.5f;
    const float ax = fmaf(c, uw, 127.5f);
    const float ay = fmaf(s, uw, 127.5f);

    float acc[BB];
#pragma unroll
    for (int b = 0; b < BB; ++b) acc[b] = 0.f;

    const int h0 = hc * 32;
    for (int i = 0; i < 32; ++i) {
        const float uh = (float)(h0 + i) - 127.5f;
        const float ix = fmaf(-s, uh, ax);
        const float iy = fmaf(c, uh, ay);
        const float x0f = floorf(ix), y0f = floorf(iy);
        const float wx1 = ix - x0f, wy1 = iy - y0f;
        const float wx0 = 1.f - wx1, wy0 = 1.f - wy1;
        const int x0 = (int)x0f, y0 = (int)y0f;
        const float vx0 = ((unsigned)x0 < 256u) ? wx0 : 0.f;
        const float vx1 = ((unsigned)(x0 + 1) < 256u) ? wx1 : 0.f;
        const float vy0 = ((unsigned)y0 < 256u) ? wy0 : 0.f;
        const float vy1 = ((unsigned)(y0 + 1) < 256u) ? wy1 : 0.f;
        const int x0c = min(max(x0, 0), 255);
        const int x1c = min(max(x0 + 1, 0), 255);
        const int y0c = min(max(y0, 0), 255);
        const int y1c = min(max(y0 + 1, 0), 255);
        const float w00 = vx0 * vy0, w10 = vx1 * vy0;
        const float w01 = vx0 * vy1, w11 = vx1 * vy1;
        const int l00 = y0c * DD + x0c, l10 = y0c * DD + x1c;
        const int l01 = y1c * DD + x0c, l11 = y1c * DD + x1c;
#pragma unroll
        for (int b = 0; b < BB; ++b) {
            const float* ib = x + (size_t)b * DD * DD;
            acc[b] = fmaf(ib[l00], w00, acc[b]);
            acc[b] = fmaf(ib[l10], w10, acc[b]);
            acc[b] = fmaf(ib[l01], w01, acc[b]);
            acc[b] = fmaf(ib[l11], w11, acc[b]);
        }
    }

    const float sc = 1.0f / 256.0f;
    float* o = out + (size_t)a * DD + w;
#pragma unroll
    for (int b = 0; b < BB; ++b)
        atomicAdd(o + (size_t)b * NA * DD, acc[b] * sc);
}

extern "C" void kernel_launch(void* const* d_in, const int* in_sizes, int n_in,
                              void* d_out, int out_size, void* d_ws, size_t ws_size,
                              hipStream_t stream) {
    const float* x = (const float*)d_in[0];
    float* out = (float*)d_out;

    const size_t need = 2ull * DD * DD * sizeof(uint4);  // 2 MiB
    if (ws_size >= need) {
        uint4* pN = (uint4*)d_ws;
        uint4* pT = pN + (size_t)DD * DD;
        pack_f16<<<256, 256, 0, stream>>>(x, pN, pT);
        radon_pk<<<dim3(NA, 4), 256, 0, stream>>>(pN, pT, out);
    } else {
        (void)hipMemsetAsync(d_out, 0, (size_t)out_size * sizeof(float), stream);
        radon_direct<<<dim3(NA, 8), 256, 0, stream>>>(x, out);
    }
}